// Round 8
// baseline (99.669 us; speedup 1.0000x reference)
//
#include <hip/hip_runtime.h>

// TanhAttention: B=4, L=512, D=256
//   scores[b,i,j] = sum_d tanh(H[b,i,d]+H[b,j,d]) * w[d] + bias
//   alpha = softmax_j(scores); r = alpha @ H
// Outputs concatenated: r (524288 floats) then alpha (1048576 floats).
//
// Math: tanh(x) = 1 - 2/(1+e^{2x}); with E = exp2(K*h), K = 2*log2(e):
//   e^{2(hi+hj)} = Ei*Ej  ->  score_shifted = -2*sum_d w_d * rcp(fma(Ei,Ej,1))
// (softmax shift cancels sum(w)+bias -> bias unused; symmetric -> upper tiles only).
//
// R7: R6's 1088 single-wave blocks = 1.06 waves/SIMD -> all latency exposed (only
// -5us despite 4x LDS / 2x trans cuts). Fix BOTH occupancy and instr count:
// 16x16 tile per wave, full D -> 2112 waves = 2.06/SIMD; private dbuf E-staging
// (zero barriers); 2i x 2j x 4d micro-tile, minimal b128 LDS (each E read once);
// slot stride 36 -> every Ei/Ej read instruction covers all 32 banks once.
// Pipe model/CU: trans ~8.4K cyc, LDS ~12.7K cyc -> score ~5-7us.

#define B_ 4
#define L_ 512
#define D_ 256
#define NT16 32         // L_/16
#define NTRI16 528      // 32*33/2 upper-tri 16x16 tiles per batch
#define DT 32           // d-tile
#define NDT 8           // D_/DT
#define ST 36           // staging slot stride (dwords): conflict-free, 16B-aligned
#define SCT 20          // epilogue scratch stride

typedef float v4f __attribute__((ext_vector_type(4)));

__global__ __launch_bounds__(256) void score_kernel(
    const float* __restrict__ H, const float* __restrict__ w,
    float* __restrict__ sOut)
{
    __shared__ __align__(16) float lds[4][2][32 * ST];   // 36.9 KB; [wave][buf][slot*ST]

    const int wv   = threadIdx.x >> 6;
    const int lane = threadIdx.x & 63;
    const int tile = blockIdx.x * 4 + wv;    // 0 .. 2111
    const int b    = tile / NTRI16;
    int t = tile - b * NTRI16;
    int ti = 0;
    while (t >= NT16 - ti) { t -= NT16 - ti; ++ti; }   // wave-uniform, <=32 iters
    const int tj = ti + t;
    const int i0 = ti * 16, j0 = tj * 16;
    const float K = 2.8853900817779268f;     // 2*log2(e)
    const float* Hb = H + (size_t)b * L_ * D_;

    const int ig = lane >> 3, jg = lane & 7; // i = i0+ig+8*ii, j = j0+jg+8*jj

    // staging ownership: 32 rows (16 i + 16 j) x 8 quads = 256 quads; 4 per lane.
    // slot = staged-row index (identity: slot ii*8+ig == i-row ig+8*ii, etc.)
    int srow[4], scol[4], slot[4];
    #pragma unroll
    for (int s = 0; s < 4; ++s) {
        int idx = lane + 64 * s;
        int r = idx >> 3, q = idx & 7;
        srow[s] = (r < 16) ? (i0 + r) : (j0 + r - 16);
        scol[s] = 4 * q;
        slot[s] = r;
    }

    float* const buf[2] = { &lds[wv][0][0], &lds[wv][1][0] };

    // prologue: stage dt=0 (E = exp2(K*h))
    #pragma unroll
    for (int s = 0; s < 4; ++s) {
        float4 hv = *(const float4*)(Hb + srow[s] * D_ + scol[s]);
        v4f ev;
        ev.x = __builtin_amdgcn_exp2f(hv.x * K);
        ev.y = __builtin_amdgcn_exp2f(hv.y * K);
        ev.z = __builtin_amdgcn_exp2f(hv.z * K);
        ev.w = __builtin_amdgcn_exp2f(hv.w * K);
        *(v4f*)&buf[0][slot[s] * ST + scol[s]] = ev;
    }

    v4f acc[2][2];
    #pragma unroll
    for (int ii = 0; ii < 2; ++ii)
        #pragma unroll
        for (int jj = 0; jj < 2; ++jj) acc[ii][jj] = (v4f){0.f, 0.f, 0.f, 0.f};

    for (int dt = 0; dt < NDT; ++dt) {
        const int cur   = dt & 1;
        const bool more = (dt + 1 < NDT);
        float4 nx[4];
        if (more) {
            const int dn = (dt + 1) * DT;
            #pragma unroll
            for (int s = 0; s < 4; ++s)
                nx[s] = *(const float4*)(Hb + srow[s] * D_ + dn + scol[s]);
        }
        __builtin_amdgcn_wave_barrier();   // pin stage-writes before these reads

        #pragma unroll
        for (int q = 0; q < 8; ++q) {      // 4-d block per step
            const float4 wq = *(const float4*)(w + dt * DT + 4 * q);  // uniform -> s_load
            v4f wvv; wvv.x = wq.x; wvv.y = wq.y; wvv.z = wq.z; wvv.w = wq.w;
            v4f Ei[2], Ej[2];
            #pragma unroll
            for (int ii = 0; ii < 2; ++ii)   // slots ii*8+ig: all 32 banks once
                Ei[ii] = *(const v4f*)&buf[cur][(ii * 8 + ig) * ST + 4 * q];
            #pragma unroll
            for (int jj = 0; jj < 2; ++jj)   // slots 16+jj*8+jg: likewise
                Ej[jj] = *(const v4f*)&buf[cur][(16 + jj * 8 + jg) * ST + 4 * q];
            #pragma unroll
            for (int ii = 0; ii < 2; ++ii)
                #pragma unroll
                for (int jj = 0; jj < 2; ++jj) {
                    v4f den = Ei[ii] * Ej[jj] + 1.0f;   // fma
                    v4f rr;
                    rr.x = __builtin_amdgcn_rcpf(den.x);
                    rr.y = __builtin_amdgcn_rcpf(den.y);
                    rr.z = __builtin_amdgcn_rcpf(den.z);
                    rr.w = __builtin_amdgcn_rcpf(den.w);
                    acc[ii][jj] += wvv * rr;
                }
        }

        if (more) {
            const int nb = 1 - cur;
            #pragma unroll
            for (int s = 0; s < 4; ++s) {
                v4f ev;
                ev.x = __builtin_amdgcn_exp2f(nx[s].x * K);
                ev.y = __builtin_amdgcn_exp2f(nx[s].y * K);
                ev.z = __builtin_amdgcn_exp2f(nx[s].z * K);
                ev.w = __builtin_amdgcn_exp2f(nx[s].w * K);
                *(v4f*)&buf[nb][slot[s] * ST + scol[s]] = ev;
            }
        }
    }

    // ---- epilogue: scatter shifted scores into scratch (buf0; last reads hit buf1) ----
    float* sc = buf[0];
    __builtin_amdgcn_wave_barrier();
    #pragma unroll
    for (int ii = 0; ii < 2; ++ii)
        #pragma unroll
        for (int jj = 0; jj < 2; ++jj) {
            v4f a = acc[ii][jj];
            sc[(ig + 8 * ii) * SCT + (jg + 8 * jj)] = -2.0f * (a.x + a.y + a.z + a.w);
        }
    __builtin_amdgcn_wave_barrier();

    // upper write: 16 rows x 16 cols, b128 (scratch reads 16B-aligned: 80r+16q)
    {
        const int r = lane >> 2, qj = lane & 3;
        v4f val = *(const v4f*)&sc[r * SCT + 4 * qj];
        *(v4f*)&sOut[((size_t)b * L_ + i0 + r) * L_ + j0 + 4 * qj] = val;
    }
    // mirror write (off-diagonal): transposed 16x16
    if (ti != tj) {
        const int jm = lane >> 2, qi = lane & 3;
        v4f mv;
        mv.x = sc[(4 * qi + 0) * SCT + jm];
        mv.y = sc[(4 * qi + 1) * SCT + jm];
        mv.z = sc[(4 * qi + 2) * SCT + jm];
        mv.w = sc[(4 * qi + 3) * SCT + jm];
        *(v4f*)&sOut[((size_t)b * L_ + j0 + jm) * L_ + i0 + 4 * qi] = mv;
    }
}

// Phase 2: 512 blocks x 256 thr; 4 rows/block (2 blocks/CU). Softmax in place,
// then r-phase: wave w owns j in [128w,128w+128), partial r for all 4 rows
// (H[b] read once per block), LDS reduce across waves.
__global__ __launch_bounds__(256) void softmax_r_kernel(
    const float* __restrict__ H, float* __restrict__ rOut, float* __restrict__ aOut)
{
    __shared__ float sc[4][L_];      // alpha rows, 8 KB
    __shared__ float pr[4][4][D_];   // per-wave partial r, 16 KB

    const int tid  = threadIdx.x;
    const int blk  = blockIdx.x;     // 0..511
    const int b    = blk >> 7;
    const int i0   = (blk & 127) * 4;
    const int wv   = tid >> 6;       // wave 0..3
    const int lane = tid & 63;
    const float* Hb = H + (size_t)b * L_ * D_;
    const float L2E = 1.4426950408889634f;

    // ---- softmax: wave wv handles row wv ----
    {
        const int row = wv;
        float* aRow = aOut + ((size_t)b * L_ + i0 + row) * L_;
        float v[8];
        float m = -1e30f;
        #pragma unroll
        for (int k = 0; k < 8; ++k) {
            v[k] = aRow[lane + 64 * k];      // coalesced score reads (L2-hot)
            m = fmaxf(m, v[k]);
        }
        #pragma unroll
        for (int off = 1; off < 64; off <<= 1)
            m = fmaxf(m, __shfl_xor(m, off, 64));
        float s = 0.0f;
        #pragma unroll
        for (int k = 0; k < 8; ++k) {
            v[k] = __builtin_amdgcn_exp2f((v[k] - m) * L2E);
            s += v[k];
        }
        #pragma unroll
        for (int off = 1; off < 64; off <<= 1)
            s += __shfl_xor(s, off, 64);
        const float inv = __builtin_amdgcn_rcpf(s);
        #pragma unroll
        for (int k = 0; k < 8; ++k) {
            float a = v[k] * inv;
            sc[row][lane + 64 * k] = a;
            aRow[lane + 64 * k] = a;         // overwrite scores with alpha in place
        }
    }
    __syncthreads();

    // ---- r-phase: wave-cooperative over j ----
    const int jbase = 128 * wv;
    v4f racc[4];
    #pragma unroll
    for (int r = 0; r < 4; ++r) racc[r] = (v4f){0.f, 0.f, 0.f, 0.f};
    const v4f* Hb4 = (const v4f*)Hb;         // [512][64]

    for (int js = 0; js < 128; js += 4) {
        v4f av[4];
        #pragma unroll
        for (int r = 0; r < 4; ++r)
            av[r] = *(const v4f*)&sc[r][jbase + js];   // b128 uniform broadcast
        #pragma unroll
        for (int q = 0; q < 4; ++q) {
            v4f h = Hb4[(size_t)(jbase + js + q) * (D_ / 4) + lane];
            #pragma unroll
            for (int r = 0; r < 4; ++r)
                racc[r] += av[r][q] * h;
        }
    }
    #pragma unroll
    for (int r = 0; r < 4; ++r)
        *(v4f*)&pr[wv][r][4 * lane] = racc[r];
    __syncthreads();

    // ---- reduce 4 wave-partials, write r ----
    const int fq  = tid & 63;       // float4 index in D
    const int row = tid >> 6;       // 0..3
    v4f s = *(const v4f*)&pr[0][row][4 * fq];
    s += *(const v4f*)&pr[1][row][4 * fq];
    s += *(const v4f*)&pr[2][row][4 * fq];
    s += *(const v4f*)&pr[3][row][4 * fq];
    *(v4f*)&rOut[((size_t)b * L_ + i0 + row) * D_ + 4 * fq] = s;
}

extern "C" void kernel_launch(void* const* d_in, const int* in_sizes, int n_in,
                              void* d_out, int out_size, void* d_ws, size_t ws_size,
                              hipStream_t stream) {
    const float* H = (const float*)d_in[0];
    const float* w = (const float*)d_in[1];
    // d_in[2] (bias) unused: softmax shift-invariance cancels it.
    float* rOut = (float*)d_out;
    float* aOut = rOut + (size_t)B_ * L_ * D_;   // alpha region doubles as score scratch

    score_kernel<<<dim3(B_ * NTRI16 / 4), 256, 0, stream>>>(H, w, aOut);
    softmax_r_kernel<<<dim3(B_ * (L_ / 4)), 256, 0, stream>>>(H, rOut, aOut);
}